// Round 25
// baseline (50.248 us; speedup 1.0000x reference)
//
#include <hip/hip_runtime.h>
#include <math.h>

#define N_IMG 64
#define D_CH  128
#define P_PIX 4096
#define K_CL  32
#define S_SPL 8
#define P_BLK (P_PIX / S_SPL)   // 512 pixels per block
#define TP    32                // pixels per tile
#define N_TILE (P_BLK / TP)     // 16 tiles

typedef __attribute__((ext_vector_type(8))) short bf16x8;
typedef __attribute__((ext_vector_type(4))) float f32x4;

#define MFMA(a, b, c) __builtin_amdgcn_mfma_f32_16x16x32_bf16(a, b, c, 0, 0, 0)

// LDS-release barrier (no vmcnt drain): prefetch loads stay in flight.
#define BAR() do {                                            \
    asm volatile("s_waitcnt lgkmcnt(0)" ::: "memory");        \
    __builtin_amdgcn_s_barrier();                             \
} while (0)

// RNE bf16 (zero-mean residual) — for x and a', whose lo-terms we drop.
static __device__ __forceinline__ ushort f2bf_rne(float f) {
    unsigned u = __float_as_uint(f);
    unsigned r = u + 0x7fffu + ((u >> 16) & 1u);
    return (ushort)(r >> 16);
}
static __device__ __forceinline__ ushort4 rne4(float a, float b, float c, float d) {
    ushort4 h;
    h.x = f2bf_rne(a); h.y = f2bf_rne(b); h.z = f2bf_rne(c); h.w = f2bf_rne(d);
    return h;
}

// Truncation split: f = hi + lo + O(2^-17 |f|) — for w only (register-resident).
static __device__ __forceinline__ void split4t(float a, float b, float c, float d,
                                               ushort4 &h, ushort4 &l) {
    unsigned ua = __float_as_uint(a), ub = __float_as_uint(b);
    unsigned uc = __float_as_uint(c), ud = __float_as_uint(d);
    h.x = (ushort)(ua >> 16); h.y = (ushort)(ub >> 16);
    h.z = (ushort)(uc >> 16); h.w = (ushort)(ud >> 16);
    float ra = a - __uint_as_float(ua & 0xffff0000u);
    float rb = b - __uint_as_float(ub & 0xffff0000u);
    float rc = c - __uint_as_float(uc & 0xffff0000u);
    float rd = d - __uint_as_float(ud & 0xffff0000u);
    l.x = (ushort)(__float_as_uint(ra) >> 16);
    l.y = (ushort)(__float_as_uint(rb) >> 16);
    l.z = (ushort)(__float_as_uint(rc) >> 16);
    l.w = (ushort)(__float_as_uint(rd) >> 16);
}

// Stage tile (tt) from regs (xv,tv) into xT + xD[(tt)&1] + pbuf (hi-only RNE),
// then prefetch regs for tile (tt)+1. Placed in GEMM2's phase (after b4).
#define STAGE_AND_PREFETCH(tt) do {                                          \
    const int cc_ = (tt) & 1;                                                \
    _Pragma("unroll")                                                        \
    for (int it = 0; it < 4; ++it) {                                         \
        int d_ = it * 32 + (tid >> 3);                                       \
        *(ushort4*)&xDh[cc_][d_ * 40 + 4 * (tid & 7)] =                      \
            rne4(xv[it].x, xv[it].y, xv[it].z, xv[it].w);                    \
    }                                                                        \
    float sq_ = 0.f;                                                         \
    _Pragma("unroll")                                                        \
    for (int c_ = 0; c_ < 4; ++c_) {                                         \
        *(ushort4*)&xTh[pT * 136 + dbase + 4 * c_] =                         \
            rne4(tv[4*c_+0], tv[4*c_+1], tv[4*c_+2], tv[4*c_+3]);            \
        sq_ += tv[4*c_+0]*tv[4*c_+0] + tv[4*c_+1]*tv[4*c_+1]                 \
             + tv[4*c_+2]*tv[4*c_+2] + tv[4*c_+3]*tv[4*c_+3];                \
    }                                                                        \
    sq_ += __shfl_xor(sq_, 32);                                              \
    if (l < 32) pbuf[wid][pT] = sq_;                                         \
    if ((tt) + 1 < N_TILE) {                                                 \
        const float* xt2_ = xin + ((tt) + 1) * TP;                           \
        _Pragma("unroll")                                                    \
        for (int it = 0; it < 4; ++it) {                                     \
            int d_ = it * 32 + (tid >> 3);                                   \
            xv[it] = *(const float4*)(xt2_ + d_ * P_PIX + 4 * (tid & 7));    \
        }                                                                    \
        _Pragma("unroll")                                                    \
        for (int j_ = 0; j_ < 16; ++j_)                                      \
            tv[j_] = xt2_[(size_t)(dbase + j_) * P_PIX + pT];                \
    }                                                                        \
} while (0)

__global__ __launch_bounds__(256)
void netvlad_main(const float* __restrict__ x, const float* __restrict__ w,
                  float* __restrict__ aggp, float* __restrict__ asump)
{
    __shared__ __align__(16) ushort xTh[32 * 136];
    __shared__ __align__(16) ushort xDh[2][128 * 40];
    __shared__ __align__(16) ushort aph[2][32 * 40];
    __shared__ float pbuf[4][32];   // per-wave ssq partials (pixel-indexed)
    __shared__ float asw[4][16];

    const int tid = threadIdx.x;
    const int n   = blockIdx.x >> 3;
    const int ps  = blockIdx.x & 7;

    const int l   = tid & 63;
    const int wid = tid >> 6;
    const int q   = l >> 4;       // 16-lane group
    const int ln  = l & 15;
    const int mt  = wid >> 1;     // GEMM1 pixel m-tile (0/1)
    const int kh  = wid & 1;      // which k-half THIS wave writes (dedup parity)

    // ---- preload conv_w fragments, BOTH k-halves (hi/lo bf16) ----
    bf16x8 wh[2][4], wl[2][4];
    #pragma unroll
    for (int n2 = 0; n2 < 2; ++n2)
        #pragma unroll
        for (int kk = 0; kk < 4; ++kk) {
            const float* wp = w + (n2 * 16 + ln) * D_CH + kk * 32 + 8 * q;
            float4 wa = *(const float4*)wp;
            float4 wb = *(const float4*)(wp + 4);
            ushort4 h1, l1, h2, l2;
            split4t(wa.x, wa.y, wa.z, wa.w, h1, l1);
            split4t(wb.x, wb.y, wb.z, wb.w, h2, l2);
            wh[n2][kk][0] = (short)h1.x; wh[n2][kk][1] = (short)h1.y;
            wh[n2][kk][2] = (short)h1.z; wh[n2][kk][3] = (short)h1.w;
            wh[n2][kk][4] = (short)h2.x; wh[n2][kk][5] = (short)h2.y;
            wh[n2][kk][6] = (short)h2.z; wh[n2][kk][7] = (short)h2.w;
            wl[n2][kk][0] = (short)l1.x; wl[n2][kk][1] = (short)l1.y;
            wl[n2][kk][2] = (short)l1.z; wl[n2][kk][3] = (short)l1.w;
            wl[n2][kk][4] = (short)l2.x; wl[n2][kk][5] = (short)l2.y;
            wl[n2][kk][6] = (short)l2.z; wl[n2][kk][7] = (short)l2.w;
        }

    f32x4 acc2[2][2];   // aggT accumulators: [m-subtile(d)][n-tile(k)]
    #pragma unroll
    for (int a = 0; a < 2; ++a)
        #pragma unroll
        for (int b = 0; b < 2; ++b)
            acc2[a][b] = (f32x4){0.f, 0.f, 0.f, 0.f};
    float asacc = 0.0f;

    const float* xin = x + (size_t)n * D_CH * P_PIX + ps * P_BLK;

    const int pT    = tid & 31;
    const int dbase = (tid >> 5) * 16;

    // ---- prologue: load tile 0 regs, stage(0), prefetch tile 1 ----
    float4 xv[4];
    float  tv[16];
    {
        const float* xt = xin;
        #pragma unroll
        for (int it = 0; it < 4; ++it) {
            int d = it * 32 + (tid >> 3);
            xv[it] = *(const float4*)(xt + d * P_PIX + 4 * (tid & 7));
        }
        #pragma unroll
        for (int j = 0; j < 16; ++j)
            tv[j] = xt[(size_t)(dbase + j) * P_PIX + pT];
    }
    STAGE_AND_PREFETCH(0);

    for (int t = 0; t < N_TILE; ++t) {
        const int c = t & 1;
        BAR();                                             // b1: stage(t) visible

        // ---- per-wave 1/||x||: all waves, in-register ----
        float spx, spy, spz, spw;
        {
            int pp = l & 31;
            int jb = (l >> 5) * 2;
            float vsq = pbuf[jb][pp] + pbuf[jb + 1][pp];
            vsq += __shfl_xor(vsq, 32);
            float sSl = 1.0f / fmaxf(sqrtf(vsq), 1e-12f);  // lane holds sS[p=l&31]
            int p0 = mt * 16 + 4 * q;
            spx = __shfl(sSl, p0 + 0);
            spy = __shfl(sSl, p0 + 1);
            spz = __shfl(sSl, p0 + 2);
            spw = __shfl(sSl, p0 + 3);
        }

        // ===== GEMM1 (dup): logits for BOTH k-halves, A reads shared =========
        f32x4 acc1_0 = (f32x4){0.f, 0.f, 0.f, 0.f};
        f32x4 acc1_1 = (f32x4){0.f, 0.f, 0.f, 0.f};
        #pragma unroll
        for (int kk = 0; kk < 4; ++kk) {
            int ia = (mt * 16 + ln) * 136 + kk * 32 + 8 * q;
            bf16x8 Ah = *(const bf16x8*)&xTh[ia];
            acc1_0 = MFMA(Ah, wh[0][kk], acc1_0);
            acc1_0 = MFMA(Ah, wl[0][kk], acc1_0);
            acc1_1 = MFMA(Ah, wh[1][kk], acc1_1);
            acc1_1 = MFMA(Ah, wl[1][kk], acc1_1);
        }

        // ===== softmax over k=32, fully in-wave (no cross-wave exchange) =====
        float e0[4], e1[4], s[4];
        e0[0] = __builtin_expf(acc1_0[0] * spx);
        e0[1] = __builtin_expf(acc1_0[1] * spy);
        e0[2] = __builtin_expf(acc1_0[2] * spz);
        e0[3] = __builtin_expf(acc1_0[3] * spw);
        e1[0] = __builtin_expf(acc1_1[0] * spx);
        e1[1] = __builtin_expf(acc1_1[1] * spy);
        e1[2] = __builtin_expf(acc1_1[2] * spz);
        e1[3] = __builtin_expf(acc1_1[3] * spw);
        #pragma unroll
        for (int r = 0; r < 4; ++r) {
            s[r] = e0[r] + e1[r];
            s[r] += __shfl_xor(s[r], 1);
            s[r] += __shfl_xor(s[r], 2);
            s[r] += __shfl_xor(s[r], 4);
            s[r] += __shfl_xor(s[r], 8);
        }
        {
            float rt[4];
            #pragma unroll
            for (int r = 0; r < 4; ++r) rt[r] = __builtin_amdgcn_rcpf(s[r]);
            float sm[4];
            #pragma unroll
            for (int r = 0; r < 4; ++r)
                sm[r] = (kh ? e1[r] : e0[r]) * rt[r];   // this wave's k-half
            asacc += sm[0] + sm[1] + sm[2] + sm[3];
            int ib = (kh * 16 + ln) * 40 + mt * 16 + 4 * q;
            *(ushort4*)&aph[c][ib] =
                rne4(sm[0] * spx, sm[1] * spy, sm[2] * spz, sm[3] * spw);
        }
        BAR();                                             // b4: a'[c] visible;
                                                           //  xT/pbuf reads done

        // ====== GEMM2(t) on dbuf[c]: A=rne(x), B=rne(a')  ||  stage(t+1) ======
        bf16x8 A2h[2], B2h[2];
        #pragma unroll
        for (int m2 = 0; m2 < 2; ++m2) {
            int ia = ((2 * wid + m2) * 16 + ln) * 40 + 8 * q;
            A2h[m2] = *(const bf16x8*)&xDh[c][ia];
        }
        #pragma unroll
        for (int n2 = 0; n2 < 2; ++n2) {
            int ib = (n2 * 16 + ln) * 40 + 8 * q;
            B2h[n2] = *(const bf16x8*)&aph[c][ib];
        }
        #pragma unroll
        for (int m2 = 0; m2 < 2; ++m2)
            #pragma unroll
            for (int n2 = 0; n2 < 2; ++n2)
                acc2[m2][n2] = MFMA(A2h[m2], B2h[n2], acc2[m2][n2]);
        if (t + 1 < N_TILE) {
            STAGE_AND_PREFETCH(t + 1);   // overlaps GEMM2's MFMA/DS-read shadow
        }
    }

    // ================= epilogue: partials to workspace =======================
    const int base = ((n * S_SPL + ps) * K_CL) * D_CH;
    #pragma unroll
    for (int m2 = 0; m2 < 2; ++m2)
        #pragma unroll
        for (int n2 = 0; n2 < 2; ++n2) {
            int k = n2 * 16 + ln;
            #pragma unroll
            for (int r = 0; r < 4; ++r) {
                int d = (2 * wid + m2) * 16 + 4 * q + r;
                aggp[base + k * D_CH + d] = acc2[m2][n2][r];
            }
        }
    asacc += __shfl_xor(asacc, 16);
    asacc += __shfl_xor(asacc, 32);
    if (l < 16) asw[wid][l] = asacc;
    __syncthreads();
    if (tid < K_CL)
        asump[(n * S_SPL + ps) * K_CL + tid] =
            asw[tid >> 4][tid & 15] + asw[(tid >> 4) + 2][tid & 15];
}

__global__ __launch_bounds__(256)
void netvlad_finish(const float* __restrict__ aggp, const float* __restrict__ asump,
                    const float* __restrict__ cen, float* __restrict__ out)
{
    __shared__ float red[K_CL][8];
    __shared__ float gw[4];
    __shared__ float gss;
    const int tid = threadIdx.x;
    const int n = blockIdx.x;
    const int k = tid >> 3;
    const int d0 = (tid & 7) << 4;

    float v[16];
    #pragma unroll
    for (int i = 0; i < 16; ++i) v[i] = 0.0f;
    float as = 0.0f;
    for (int qq = 0; qq < S_SPL; ++qq) {
        const float* src = aggp + (((n * S_SPL + qq) * K_CL) + k) * D_CH + d0;
        #pragma unroll
        for (int c = 0; c < 4; ++c) {
            float4 t4 = *(const float4*)(src + (c << 2));
            v[4*c+0] += t4.x; v[4*c+1] += t4.y; v[4*c+2] += t4.z; v[4*c+3] += t4.w;
        }
        as += asump[(n * S_SPL + qq) * K_CL + k];
    }
    const float* cp = cen + k * D_CH + d0;
    float ssq = 0.0f;
    #pragma unroll
    for (int c = 0; c < 4; ++c) {
        float4 c4 = *(const float4*)(cp + (c << 2));
        v[4*c+0] -= as * c4.x;
        v[4*c+1] -= as * c4.y;
        v[4*c+2] -= as * c4.z;
        v[4*c+3] -= as * c4.w;
    }
    #pragma unroll
    for (int i = 0; i < 16; ++i) ssq += v[i] * v[i];
    red[k][tid & 7] = ssq;
    __syncthreads();
    float s2 = 0.0f;
    #pragma unroll
    for (int j = 0; j < 8; ++j) s2 += red[k][j];
    const float sc1 = 1.0f / fmaxf(sqrtf(s2), 1e-12f);
    #pragma unroll
    for (int i = 0; i < 16; ++i) v[i] *= sc1;
    float g = ssq * sc1 * sc1;
    #pragma unroll
    for (int off = 1; off < 64; off <<= 1) g += __shfl_xor(g, off);
    if ((tid & 63) == 0) gw[tid >> 6] = g;
    __syncthreads();
    if (tid == 0) gss = 1.0f / fmaxf(sqrtf(gw[0] + gw[1] + gw[2] + gw[3]), 1e-12f);
    __syncthreads();
    const float gsc = gss;
    float* op = out + (size_t)n * (K_CL * D_CH) + k * D_CH + d0;
    #pragma unroll
    for (int c = 0; c < 4; ++c) {
        *(float4*)(op + (c << 2)) =
            make_float4(v[4*c+0]*gsc, v[4*c+1]*gsc, v[4*c+2]*gsc, v[4*c+3]*gsc);
    }
}

extern "C" void kernel_launch(void* const* d_in, const int* in_sizes, int n_in,
                              void* d_out, int out_size, void* d_ws, size_t ws_size,
                              hipStream_t stream)
{
    const float* x   = (const float*)d_in[0];
    const float* w   = (const float*)d_in[1];
    const float* cen = (const float*)d_in[2];
    float* out = (float*)d_out;

    float* aggp  = (float*)d_ws;                                    // [64][8][32][128] = 8 MB
    float* asump = aggp + (size_t)N_IMG * S_SPL * K_CL * D_CH;      // [64][8][32]

    netvlad_main<<<N_IMG * S_SPL, 256, 0, stream>>>(x, w, aggp, asump);
    netvlad_finish<<<N_IMG, 256, 0, stream>>>(aggp, asump, cen, out);
}

// Round 26
// 46.795 us; speedup vs baseline: 1.0738x; 1.0738x over previous
//
#include <hip/hip_runtime.h>
#include <math.h>

#define N_IMG 64
#define D_CH  128
#define P_PIX 4096
#define K_CL  32
#define S_SPL 8
#define P_BLK (P_PIX / S_SPL)   // 512 pixels per block
#define TP    32                // pixels per tile
#define N_TILE (P_BLK / TP)     // 16 tiles

typedef __attribute__((ext_vector_type(8))) short bf16x8;
typedef __attribute__((ext_vector_type(4))) float f32x4;

#define MFMA(a, b, c) __builtin_amdgcn_mfma_f32_16x16x32_bf16(a, b, c, 0, 0, 0)

// LDS-release barrier (no vmcnt drain): prefetch loads stay in flight.
#define BAR() do {                                            \
    asm volatile("s_waitcnt lgkmcnt(0)" ::: "memory");        \
    __builtin_amdgcn_s_barrier();                             \
} while (0)

// RNE bf16 (zero-mean residual) — for x and a', whose lo-terms we drop.
static __device__ __forceinline__ ushort f2bf_rne(float f) {
    unsigned u = __float_as_uint(f);
    unsigned r = u + 0x7fffu + ((u >> 16) & 1u);
    return (ushort)(r >> 16);
}
static __device__ __forceinline__ ushort4 rne4(float a, float b, float c, float d) {
    ushort4 h;
    h.x = f2bf_rne(a); h.y = f2bf_rne(b); h.z = f2bf_rne(c); h.w = f2bf_rne(d);
    return h;
}

// Truncation split: f = hi + lo + O(2^-17 |f|) — for w only (register-resident).
static __device__ __forceinline__ void split4t(float a, float b, float c, float d,
                                               ushort4 &h, ushort4 &l) {
    unsigned ua = __float_as_uint(a), ub = __float_as_uint(b);
    unsigned uc = __float_as_uint(c), ud = __float_as_uint(d);
    h.x = (ushort)(ua >> 16); h.y = (ushort)(ub >> 16);
    h.z = (ushort)(uc >> 16); h.w = (ushort)(ud >> 16);
    float ra = a - __uint_as_float(ua & 0xffff0000u);
    float rb = b - __uint_as_float(ub & 0xffff0000u);
    float rc = c - __uint_as_float(uc & 0xffff0000u);
    float rd = d - __uint_as_float(ud & 0xffff0000u);
    l.x = (ushort)(__float_as_uint(ra) >> 16);
    l.y = (ushort)(__float_as_uint(rb) >> 16);
    l.z = (ushort)(__float_as_uint(rc) >> 16);
    l.w = (ushort)(__float_as_uint(rd) >> 16);
}

// Stage tile (tt) from regs (xv,tv) into xT + xD[(tt)&1] + pbuf (hi-only RNE),
// then prefetch regs for tile (tt)+1. Placed in GEMM2's phase (after b4).
#define STAGE_AND_PREFETCH(tt) do {                                          \
    const int cc_ = (tt) & 1;                                                \
    _Pragma("unroll")                                                        \
    for (int it = 0; it < 4; ++it) {                                         \
        int d_ = it * 32 + (tid >> 3);                                       \
        *(ushort4*)&xDh[cc_][d_ * 40 + 4 * (tid & 7)] =                      \
            rne4(xv[it].x, xv[it].y, xv[it].z, xv[it].w);                    \
    }                                                                        \
    float sq_ = 0.f;                                                         \
    _Pragma("unroll")                                                        \
    for (int c_ = 0; c_ < 4; ++c_) {                                         \
        *(ushort4*)&xTh[pT * 136 + dbase + 4 * c_] =                         \
            rne4(tv[4*c_+0], tv[4*c_+1], tv[4*c_+2], tv[4*c_+3]);            \
        sq_ += tv[4*c_+0]*tv[4*c_+0] + tv[4*c_+1]*tv[4*c_+1]                 \
             + tv[4*c_+2]*tv[4*c_+2] + tv[4*c_+3]*tv[4*c_+3];                \
    }                                                                        \
    sq_ += __shfl_xor(sq_, 32);                                              \
    if (l < 32) pbuf[wid][pT] = sq_;                                         \
    if ((tt) + 1 < N_TILE) {                                                 \
        const float* xt2_ = xin + ((tt) + 1) * TP;                           \
        _Pragma("unroll")                                                    \
        for (int it = 0; it < 4; ++it) {                                     \
            int d_ = it * 32 + (tid >> 3);                                   \
            xv[it] = *(const float4*)(xt2_ + d_ * P_PIX + 4 * (tid & 7));    \
        }                                                                    \
        _Pragma("unroll")                                                    \
        for (int j_ = 0; j_ < 16; ++j_)                                      \
            tv[j_] = xt2_[(size_t)(dbase + j_) * P_PIX + pT];                \
    }                                                                        \
} while (0)

__global__ __launch_bounds__(256)
void netvlad_main(const float* __restrict__ x, const float* __restrict__ w,
                  float* __restrict__ aggp, float* __restrict__ asump)
{
    __shared__ __align__(16) ushort xTh[32 * 136];
    __shared__ __align__(16) ushort xDh[2][128 * 40];
    __shared__ __align__(16) ushort aph[2][32 * 40];
    __shared__ __align__(16) float  xch[4][64][4];
    __shared__ float pbuf[4][32];   // per-wave ssq partials (pixel-indexed)
    __shared__ float asw[4][16];

    const int tid = threadIdx.x;
    const int n   = blockIdx.x >> 3;
    const int ps  = blockIdx.x & 7;

    const int l   = tid & 63;
    const int wid = tid >> 6;
    const int q   = l >> 4;       // 16-lane group
    const int ln  = l & 15;
    const int mt  = wid >> 1;     // GEMM1 pixel m-tile (0/1)
    const int nt  = wid & 1;      // GEMM1/2 k n-tile (0/1)

    // ---- preload conv_w fragments into registers (hi/lo bf16), per wave's nt ----
    bf16x8 wh[4], wl[4];
    #pragma unroll
    for (int kk = 0; kk < 4; ++kk) {
        const float* wp = w + (nt * 16 + ln) * D_CH + kk * 32 + 8 * q;
        float4 wa = *(const float4*)wp;
        float4 wb = *(const float4*)(wp + 4);
        ushort4 h1, l1, h2, l2;
        split4t(wa.x, wa.y, wa.z, wa.w, h1, l1);
        split4t(wb.x, wb.y, wb.z, wb.w, h2, l2);
        wh[kk][0] = (short)h1.x; wh[kk][1] = (short)h1.y; wh[kk][2] = (short)h1.z; wh[kk][3] = (short)h1.w;
        wh[kk][4] = (short)h2.x; wh[kk][5] = (short)h2.y; wh[kk][6] = (short)h2.z; wh[kk][7] = (short)h2.w;
        wl[kk][0] = (short)l1.x; wl[kk][1] = (short)l1.y; wl[kk][2] = (short)l1.z; wl[kk][3] = (short)l1.w;
        wl[kk][4] = (short)l2.x; wl[kk][5] = (short)l2.y; wl[kk][6] = (short)l2.z; wl[kk][7] = (short)l2.w;
    }

    f32x4 acc2[2][2];   // aggT accumulators: [m-subtile(d)][n-tile(k)]
    #pragma unroll
    for (int a = 0; a < 2; ++a)
        #pragma unroll
        for (int b = 0; b < 2; ++b)
            acc2[a][b] = (f32x4){0.f, 0.f, 0.f, 0.f};
    float asacc = 0.0f;

    const float* xin = x + (size_t)n * D_CH * P_PIX + ps * P_BLK;

    const int pT    = tid & 31;
    const int dbase = (tid >> 5) * 16;

    // ---- prologue: load tile 0 regs, stage(0), prefetch tile 1 ----
    float4 xv[4];
    float  tv[16];
    {
        const float* xt = xin;
        #pragma unroll
        for (int it = 0; it < 4; ++it) {
            int d = it * 32 + (tid >> 3);
            xv[it] = *(const float4*)(xt + d * P_PIX + 4 * (tid & 7));
        }
        #pragma unroll
        for (int j = 0; j < 16; ++j)
            tv[j] = xt[(size_t)(dbase + j) * P_PIX + pT];
    }
    STAGE_AND_PREFETCH(0);

    for (int t = 0; t < N_TILE; ++t) {
        const int c = t & 1;
        BAR();                                             // b1: stage(t) visible

        // ---- per-wave 1/||x||: all waves, in-register ----
        float spx, spy, spz, spw;
        {
            int pp = l & 31;
            int jb = (l >> 5) * 2;
            float vsq = pbuf[jb][pp] + pbuf[jb + 1][pp];
            vsq += __shfl_xor(vsq, 32);
            float sSl = 1.0f / fmaxf(sqrtf(vsq), 1e-12f);  // lane holds sS[p=l&31]
            int p0 = mt * 16 + 4 * q;
            spx = __shfl(sSl, p0 + 0);
            spy = __shfl(sSl, p0 + 1);
            spz = __shfl(sSl, p0 + 2);
            spw = __shfl(sSl, p0 + 3);
        }

        // ======== GEMM1: logits (p x k), contract d — A=rne(x), full w ========
        f32x4 acc1 = (f32x4){0.f, 0.f, 0.f, 0.f};
        #pragma unroll
        for (int kk = 0; kk < 4; ++kk) {
            int ia = (mt * 16 + ln) * 136 + kk * 32 + 8 * q;
            bf16x8 Ah = *(const bf16x8*)&xTh[ia];
            acc1 = MFMA(Ah, wh[kk], acc1);
            acc1 = MFMA(Ah, wl[kk], acc1);
        }

        // ================= softmax over k (in-register, no max-sub) ===========
        float e[4], s[4];
        e[0] = __builtin_expf(acc1[0] * spx);
        e[1] = __builtin_expf(acc1[1] * spy);
        e[2] = __builtin_expf(acc1[2] * spz);
        e[3] = __builtin_expf(acc1[3] * spw);
        #pragma unroll
        for (int r = 0; r < 4; ++r) {
            s[r] = e[r];
            s[r] += __shfl_xor(s[r], 1);
            s[r] += __shfl_xor(s[r], 2);
            s[r] += __shfl_xor(s[r], 4);
            s[r] += __shfl_xor(s[r], 8);
        }
        *(float4*)&xch[wid][l][0] = make_float4(s[0], s[1], s[2], s[3]);
        BAR();                                             // b3: partial sums
        {
            float4 po = *(const float4*)&xch[wid ^ 1][l][0];
            float rt[4];
            rt[0] = __builtin_amdgcn_rcpf(s[0] + po.x);
            rt[1] = __builtin_amdgcn_rcpf(s[1] + po.y);
            rt[2] = __builtin_amdgcn_rcpf(s[2] + po.z);
            rt[3] = __builtin_amdgcn_rcpf(s[3] + po.w);
            float sm[4];
            #pragma unroll
            for (int r = 0; r < 4; ++r) sm[r] = e[r] * rt[r];
            asacc += sm[0] + sm[1] + sm[2] + sm[3];
            int ib = (nt * 16 + ln) * 40 + mt * 16 + 4 * q;
            *(ushort4*)&aph[c][ib] =
                rne4(sm[0] * spx, sm[1] * spy, sm[2] * spz, sm[3] * spw);
        }
        BAR();                                             // b4: a'[c] visible;
                                                           //  xT/pbuf read-done

        // ====== GEMM2(t) on dbuf[c]: A=rne(x), B=rne(a')  ||  stage(t+1) ======
        bf16x8 A2h[2], B2h[2];
        #pragma unroll
        for (int m2 = 0; m2 < 2; ++m2) {
            int ia = ((2 * wid + m2) * 16 + ln) * 40 + 8 * q;
            A2h[m2] = *(const bf16x8*)&xDh[c][ia];
        }
        #pragma unroll
        for (int n2 = 0; n2 < 2; ++n2) {
            int ib = (n2 * 16 + ln) * 40 + 8 * q;
            B2h[n2] = *(const bf16x8*)&aph[c][ib];
        }
        #pragma unroll
        for (int m2 = 0; m2 < 2; ++m2)
            #pragma unroll
            for (int n2 = 0; n2 < 2; ++n2)
                acc2[m2][n2] = MFMA(A2h[m2], B2h[n2], acc2[m2][n2]);
        if (t + 1 < N_TILE) {
            STAGE_AND_PREFETCH(t + 1);   // overlaps GEMM2's MFMA/DS-read shadow
        }
    }

    // ================= epilogue: partials to workspace =======================
    const int base = ((n * S_SPL + ps) * K_CL) * D_CH;
    #pragma unroll
    for (int m2 = 0; m2 < 2; ++m2)
        #pragma unroll
        for (int n2 = 0; n2 < 2; ++n2) {
            int k = n2 * 16 + ln;
            #pragma unroll
            for (int r = 0; r < 4; ++r) {
                int d = (2 * wid + m2) * 16 + 4 * q + r;
                aggp[base + k * D_CH + d] = acc2[m2][n2][r];
            }
        }
    asacc += __shfl_xor(asacc, 16);
    asacc += __shfl_xor(asacc, 32);
    if (l < 16) asw[wid][l] = asacc;
    __syncthreads();
    if (tid < K_CL)
        asump[(n * S_SPL + ps) * K_CL + tid] =
            asw[tid >> 4][tid & 15] + asw[(tid >> 4) + 2][tid & 15];
}

__global__ __launch_bounds__(256)
void netvlad_finish(const float* __restrict__ aggp, const float* __restrict__ asump,
                    const float* __restrict__ cen, float* __restrict__ out)
{
    __shared__ float red[K_CL][8];
    __shared__ float gw[4];
    __shared__ float gss;
    const int tid = threadIdx.x;
    const int n = blockIdx.x;
    const int k = tid >> 3;
    const int d0 = (tid & 7) << 4;

    float v[16];
    #pragma unroll
    for (int i = 0; i < 16; ++i) v[i] = 0.0f;
    float as = 0.0f;
    for (int qq = 0; qq < S_SPL; ++qq) {
        const float* src = aggp + (((n * S_SPL + qq) * K_CL) + k) * D_CH + d0;
        #pragma unroll
        for (int c = 0; c < 4; ++c) {
            float4 t4 = *(const float4*)(src + (c << 2));
            v[4*c+0] += t4.x; v[4*c+1] += t4.y; v[4*c+2] += t4.z; v[4*c+3] += t4.w;
        }
        as += asump[(n * S_SPL + qq) * K_CL + k];
    }
    const float* cp = cen + k * D_CH + d0;
    float ssq = 0.0f;
    #pragma unroll
    for (int c = 0; c < 4; ++c) {
        float4 c4 = *(const float4*)(cp + (c << 2));
        v[4*c+0] -= as * c4.x;
        v[4*c+1] -= as * c4.y;
        v[4*c+2] -= as * c4.z;
        v[4*c+3] -= as * c4.w;
    }
    #pragma unroll
    for (int i = 0; i < 16; ++i) ssq += v[i] * v[i];
    red[k][tid & 7] = ssq;
    __syncthreads();
    float s2 = 0.0f;
    #pragma unroll
    for (int j = 0; j < 8; ++j) s2 += red[k][j];
    const float sc1 = 1.0f / fmaxf(sqrtf(s2), 1e-12f);
    #pragma unroll
    for (int i = 0; i < 16; ++i) v[i] *= sc1;
    float g = ssq * sc1 * sc1;
    #pragma unroll
    for (int off = 1; off < 64; off <<= 1) g += __shfl_xor(g, off);
    if ((tid & 63) == 0) gw[tid >> 6] = g;
    __syncthreads();
    if (tid == 0) gss = 1.0f / fmaxf(sqrtf(gw[0] + gw[1] + gw[2] + gw[3]), 1e-12f);
    __syncthreads();
    const float gsc = gss;
    float* op = out + (size_t)n * (K_CL * D_CH) + k * D_CH + d0;
    #pragma unroll
    for (int c = 0; c < 4; ++c) {
        *(float4*)(op + (c << 2)) =
            make_float4(v[4*c+0]*gsc, v[4*c+1]*gsc, v[4*c+2]*gsc, v[4*c+3]*gsc);
    }
}

extern "C" void kernel_launch(void* const* d_in, const int* in_sizes, int n_in,
                              void* d_out, int out_size, void* d_ws, size_t ws_size,
                              hipStream_t stream)
{
    const float* x   = (const float*)d_in[0];
    const float* w   = (const float*)d_in[1];
    const float* cen = (const float*)d_in[2];
    float* out = (float*)d_out;

    float* aggp  = (float*)d_ws;                                    // [64][8][32][128] = 8 MB
    float* asump = aggp + (size_t)N_IMG * S_SPL * K_CL * D_CH;      // [64][8][32]

    netvlad_main<<<N_IMG * S_SPL, 256, 0, stream>>>(x, w, aggp, asump);
    netvlad_finish<<<N_IMG, 256, 0, stream>>>(aggp, asump, cen, out);
}

// Round 27
// 45.296 us; speedup vs baseline: 1.1093x; 1.0331x over previous
//
#include <hip/hip_runtime.h>
#include <math.h>

#define N_IMG 64
#define D_CH  128
#define P_PIX 4096
#define K_CL  32
#define S_SPL 8
#define P_BLK (P_PIX / S_SPL)   // 512 pixels per block
#define TP    64                // pixels per tile (pure scaling of R24)
#define N_TILE (P_BLK / TP)     // 8 tiles
#define XDS   72                // xD row stride (ushorts): 64 px + 8 pad
#define APS   72                // a' row stride
#define XTS   136               // xT row stride: 128 d + 8 pad

typedef __attribute__((ext_vector_type(8))) short bf16x8;
typedef __attribute__((ext_vector_type(4))) float f32x4;

#define MFMA(a, b, c) __builtin_amdgcn_mfma_f32_16x16x32_bf16(a, b, c, 0, 0, 0)

// LDS-release barrier (no vmcnt drain): prefetch loads stay in flight.
#define BAR() do {                                            \
    asm volatile("s_waitcnt lgkmcnt(0)" ::: "memory");        \
    __builtin_amdgcn_s_barrier();                             \
} while (0)

// RNE bf16 (zero-mean residual) — for x and a', whose lo-terms we drop.
static __device__ __forceinline__ ushort f2bf_rne(float f) {
    unsigned u = __float_as_uint(f);
    unsigned r = u + 0x7fffu + ((u >> 16) & 1u);
    return (ushort)(r >> 16);
}
static __device__ __forceinline__ ushort4 rne4(float a, float b, float c, float d) {
    ushort4 h;
    h.x = f2bf_rne(a); h.y = f2bf_rne(b); h.z = f2bf_rne(c); h.w = f2bf_rne(d);
    return h;
}

// Truncation split: f = hi + lo + O(2^-17 |f|) — for w only (register-resident).
static __device__ __forceinline__ void split4t(float a, float b, float c, float d,
                                               ushort4 &h, ushort4 &l) {
    unsigned ua = __float_as_uint(a), ub = __float_as_uint(b);
    unsigned uc = __float_as_uint(c), ud = __float_as_uint(d);
    h.x = (ushort)(ua >> 16); h.y = (ushort)(ub >> 16);
    h.z = (ushort)(uc >> 16); h.w = (ushort)(ud >> 16);
    float ra = a - __uint_as_float(ua & 0xffff0000u);
    float rb = b - __uint_as_float(ub & 0xffff0000u);
    float rc = c - __uint_as_float(uc & 0xffff0000u);
    float rd = d - __uint_as_float(ud & 0xffff0000u);
    l.x = (ushort)(__float_as_uint(ra) >> 16);
    l.y = (ushort)(__float_as_uint(rb) >> 16);
    l.z = (ushort)(__float_as_uint(rc) >> 16);
    l.w = (ushort)(__float_as_uint(rd) >> 16);
}

// Stage tile (tt) from regs (xv,tv) into xT + xD[(tt)&1] + pbuf (hi-only RNE),
// then prefetch regs for tile (tt)+1. Placed in GEMM2's phase (after b4).
// Coalesced: xD float4 rows, xT 64B-chunked columns (same patterns as R24, 2x count).
#define STAGE_AND_PREFETCH(tt) do {                                          \
    const int cc_ = (tt) & 1;                                                \
    _Pragma("unroll")                                                        \
    for (int it = 0; it < 8; ++it) {                                         \
        int d_ = it * 16 + (tid >> 4);                                       \
        *(ushort4*)&xDh[cc_][d_ * XDS + 4 * (tid & 15)] =                    \
            rne4(xv[it].x, xv[it].y, xv[it].z, xv[it].w);                    \
    }                                                                        \
    float sq_ = 0.f;                                                         \
    _Pragma("unroll")                                                        \
    for (int c_ = 0; c_ < 8; ++c_) {                                         \
        *(ushort4*)&xTh[pT * XTS + dbase + 4 * c_] =                         \
            rne4(tv[4*c_+0], tv[4*c_+1], tv[4*c_+2], tv[4*c_+3]);            \
        sq_ += tv[4*c_+0]*tv[4*c_+0] + tv[4*c_+1]*tv[4*c_+1]                 \
             + tv[4*c_+2]*tv[4*c_+2] + tv[4*c_+3]*tv[4*c_+3];                \
    }                                                                        \
    pbuf[wid][pT] = sq_;                                                     \
    if ((tt) + 1 < N_TILE) {                                                 \
        const float* xt2_ = xin + ((tt) + 1) * TP;                           \
        _Pragma("unroll")                                                    \
        for (int it = 0; it < 8; ++it) {                                     \
            int d_ = it * 16 + (tid >> 4);                                   \
            xv[it] = *(const float4*)(xt2_ + (size_t)d_ * P_PIX + 4 * (tid & 15)); \
        }                                                                    \
        _Pragma("unroll")                                                    \
        for (int j_ = 0; j_ < 32; ++j_)                                      \
            tv[j_] = xt2_[(size_t)(dbase + j_) * P_PIX + pT];                \
    }                                                                        \
} while (0)

__global__ __launch_bounds__(256)
void netvlad_main(const float* __restrict__ x, const float* __restrict__ w,
                  float* __restrict__ aggp, float* __restrict__ asump)
{
    __shared__ __align__(16) ushort xTh[64 * XTS];        // 17.4 KB
    __shared__ __align__(16) ushort xDh[2][128 * XDS];    // 36.9 KB
    __shared__ __align__(16) ushort aph[2][32 * APS];     //  9.2 KB
    __shared__ __align__(16) float  xch[4][64][8];        //  8.0 KB
    __shared__ float pbuf[4][64];                         //  1.0 KB
    __shared__ float asw[4][16];

    const int tid = threadIdx.x;
    const int n   = blockIdx.x >> 3;
    const int ps  = blockIdx.x & 7;

    const int l   = tid & 63;
    const int wid = tid >> 6;
    const int q   = l >> 4;       // 16-lane group
    const int ln  = l & 15;
    const int mt  = wid >> 1;     // GEMM1 pixel m-tile within each 32-px half
    const int nt  = wid & 1;      // GEMM1/2 k n-tile (0/1)

    // ---- preload conv_w fragments into registers (hi/lo bf16), per wave's nt ----
    bf16x8 wh[4], wl[4];
    #pragma unroll
    for (int kk = 0; kk < 4; ++kk) {
        const float* wp = w + (nt * 16 + ln) * D_CH + kk * 32 + 8 * q;
        float4 wa = *(const float4*)wp;
        float4 wb = *(const float4*)(wp + 4);
        ushort4 h1, l1, h2, l2;
        split4t(wa.x, wa.y, wa.z, wa.w, h1, l1);
        split4t(wb.x, wb.y, wb.z, wb.w, h2, l2);
        wh[kk][0] = (short)h1.x; wh[kk][1] = (short)h1.y; wh[kk][2] = (short)h1.z; wh[kk][3] = (short)h1.w;
        wh[kk][4] = (short)h2.x; wh[kk][5] = (short)h2.y; wh[kk][6] = (short)h2.z; wh[kk][7] = (short)h2.w;
        wl[kk][0] = (short)l1.x; wl[kk][1] = (short)l1.y; wl[kk][2] = (short)l1.z; wl[kk][3] = (short)l1.w;
        wl[kk][4] = (short)l2.x; wl[kk][5] = (short)l2.y; wl[kk][6] = (short)l2.z; wl[kk][7] = (short)l2.w;
    }

    f32x4 acc2[2][2];   // aggT accumulators: [m-subtile(d)][n-tile(k)]
    #pragma unroll
    for (int a = 0; a < 2; ++a)
        #pragma unroll
        for (int b = 0; b < 2; ++b)
            acc2[a][b] = (f32x4){0.f, 0.f, 0.f, 0.f};
    float asacc = 0.0f;

    const float* xin = x + (size_t)n * D_CH * P_PIX + ps * P_BLK;

    const int pT    = l;                 // xT pixel (0..63)
    const int dbase = wid * 32;          // xT d-chunk (one 32-d chunk per wave)

    // ---- prologue: load tile 0 regs, stage(0), prefetch tile 1 ----
    float4 xv[8];
    float  tv[32];
    {
        const float* xt = xin;
        #pragma unroll
        for (int it = 0; it < 8; ++it) {
            int d = it * 16 + (tid >> 4);
            xv[it] = *(const float4*)(xt + (size_t)d * P_PIX + 4 * (tid & 15));
        }
        #pragma unroll
        for (int j = 0; j < 32; ++j)
            tv[j] = xt[(size_t)(dbase + j) * P_PIX + pT];
    }
    STAGE_AND_PREFETCH(0);

    for (int t = 0; t < N_TILE; ++t) {
        const int c = t & 1;
        BAR();                                             // b1: stage(t) visible

        // ---- per-lane 1/||x||: lane l owns pixel l's norm ----
        float sp[2][4];
        {
            float vsq = pbuf[0][l] + pbuf[1][l] + pbuf[2][l] + pbuf[3][l];
            float sSl = 1.0f / fmaxf(sqrtf(vsq), 1e-12f);
            #pragma unroll
            for (int ph = 0; ph < 2; ++ph)
                #pragma unroll
                for (int r = 0; r < 4; ++r)
                    sp[ph][r] = __shfl(sSl, ph * 32 + mt * 16 + 4 * q + r);
        }

        // ==== GEMM1: logits for both 32-px halves, A=rne(x), full w ==========
        f32x4 acc1[2];
        #pragma unroll
        for (int ph = 0; ph < 2; ++ph) {
            acc1[ph] = (f32x4){0.f, 0.f, 0.f, 0.f};
            #pragma unroll
            for (int kk = 0; kk < 4; ++kk) {
                int ia = (ph * 32 + mt * 16 + ln) * XTS + kk * 32 + 8 * q;
                bf16x8 Ah = *(const bf16x8*)&xTh[ia];
                acc1[ph] = MFMA(Ah, wh[kk], acc1[ph]);
                acc1[ph] = MFMA(Ah, wl[kk], acc1[ph]);
            }
        }

        // ======= softmax over k (in-register, no max-sub), both halves =======
        float e[2][4], s[2][4];
        #pragma unroll
        for (int ph = 0; ph < 2; ++ph) {
            #pragma unroll
            for (int r = 0; r < 4; ++r) {
                e[ph][r] = __builtin_expf(acc1[ph][r] * sp[ph][r]);
                s[ph][r] = e[ph][r];
                s[ph][r] += __shfl_xor(s[ph][r], 1);
                s[ph][r] += __shfl_xor(s[ph][r], 2);
                s[ph][r] += __shfl_xor(s[ph][r], 4);
                s[ph][r] += __shfl_xor(s[ph][r], 8);
            }
        }
        *(float4*)&xch[wid][l][0] = make_float4(s[0][0], s[0][1], s[0][2], s[0][3]);
        *(float4*)&xch[wid][l][4] = make_float4(s[1][0], s[1][1], s[1][2], s[1][3]);
        BAR();                                             // b3: partial sums
        #pragma unroll
        for (int ph = 0; ph < 2; ++ph) {
            float4 po = *(const float4*)&xch[wid ^ 1][l][ph * 4];
            float rt[4];
            rt[0] = __builtin_amdgcn_rcpf(s[ph][0] + po.x);
            rt[1] = __builtin_amdgcn_rcpf(s[ph][1] + po.y);
            rt[2] = __builtin_amdgcn_rcpf(s[ph][2] + po.z);
            rt[3] = __builtin_amdgcn_rcpf(s[ph][3] + po.w);
            float sm[4];
            #pragma unroll
            for (int r = 0; r < 4; ++r) sm[r] = e[ph][r] * rt[r];
            asacc += sm[0] + sm[1] + sm[2] + sm[3];
            int ib = (nt * 16 + ln) * APS + ph * 32 + mt * 16 + 4 * q;
            *(ushort4*)&aph[c][ib] = rne4(sm[0] * sp[ph][0], sm[1] * sp[ph][1],
                                          sm[2] * sp[ph][2], sm[3] * sp[ph][3]);
        }
        BAR();                                             // b4: a'[c] visible;
                                                           //  xT/pbuf read-done

        // ====== GEMM2(t) on dbuf[c]: contract p=64 (2 chunks) || stage(t+1) ===
        #pragma unroll
        for (int pc = 0; pc < 2; ++pc) {
            bf16x8 A2h[2], B2h[2];
            #pragma unroll
            for (int m2 = 0; m2 < 2; ++m2) {
                int ia = ((2 * wid + m2) * 16 + ln) * XDS + pc * 32 + 8 * q;
                A2h[m2] = *(const bf16x8*)&xDh[c][ia];
            }
            #pragma unroll
            for (int n2 = 0; n2 < 2; ++n2) {
                int ib = (n2 * 16 + ln) * APS + pc * 32 + 8 * q;
                B2h[n2] = *(const bf16x8*)&aph[c][ib];
            }
            #pragma unroll
            for (int m2 = 0; m2 < 2; ++m2)
                #pragma unroll
                for (int n2 = 0; n2 < 2; ++n2)
                    acc2[m2][n2] = MFMA(A2h[m2], B2h[n2], acc2[m2][n2]);
        }
        if (t + 1 < N_TILE) {
            STAGE_AND_PREFETCH(t + 1);   // overlaps GEMM2's MFMA/DS-read shadow
        }
    }

    // ================= epilogue: partials to workspace =======================
    const int base = ((n * S_SPL + ps) * K_CL) * D_CH;
    #pragma unroll
    for (int m2 = 0; m2 < 2; ++m2)
        #pragma unroll
        for (int n2 = 0; n2 < 2; ++n2) {
            int k = n2 * 16 + ln;
            #pragma unroll
            for (int r = 0; r < 4; ++r) {
                int d = (2 * wid + m2) * 16 + 4 * q + r;
                aggp[base + k * D_CH + d] = acc2[m2][n2][r];
            }
        }
    asacc += __shfl_xor(asacc, 16);
    asacc += __shfl_xor(asacc, 32);
    if (l < 16) asw[wid][l] = asacc;
    __syncthreads();
    if (tid < K_CL)
        asump[(n * S_SPL + ps) * K_CL + tid] =
            asw[tid >> 4][tid & 15] + asw[(tid >> 4) + 2][tid & 15];
}

__global__ __launch_bounds__(256)
void netvlad_finish(const float* __restrict__ aggp, const float* __restrict__ asump,
                    const float* __restrict__ cen, float* __restrict__ out)
{
    __shared__ float red[K_CL][8];
    __shared__ float gw[4];
    __shared__ float gss;
    const int tid = threadIdx.x;
    const int n = blockIdx.x;
    const int k = tid >> 3;
    const int d0 = (tid & 7) << 4;

    float v[16];
    #pragma unroll
    for (int i = 0; i < 16; ++i) v[i] = 0.0f;
    float as = 0.0f;
    for (int qq = 0; qq < S_SPL; ++qq) {
        const float* src = aggp + (((n * S_SPL + qq) * K_CL) + k) * D_CH + d0;
        #pragma unroll
        for (int c = 0; c < 4; ++c) {
            float4 t4 = *(const float4*)(src + (c << 2));
            v[4*c+0] += t4.x; v[4*c+1] += t4.y; v[4*c+2] += t4.z; v[4*c+3] += t4.w;
        }
        as += asump[(n * S_SPL + qq) * K_CL + k];
    }
    const float* cp = cen + k * D_CH + d0;
    float ssq = 0.0f;
    #pragma unroll
    for (int c = 0; c < 4; ++c) {
        float4 c4 = *(const float4*)(cp + (c << 2));
        v[4*c+0] -= as * c4.x;
        v[4*c+1] -= as * c4.y;
        v[4*c+2] -= as * c4.z;
        v[4*c+3] -= as * c4.w;
    }
    #pragma unroll
    for (int i = 0; i < 16; ++i) ssq += v[i] * v[i];
    red[k][tid & 7] = ssq;
    __syncthreads();
    float s2 = 0.0f;
    #pragma unroll
    for (int j = 0; j < 8; ++j) s2 += red[k][j];
    const float sc1 = 1.0f / fmaxf(sqrtf(s2), 1e-12f);
    #pragma unroll
    for (int i = 0; i < 16; ++i) v[i] *= sc1;
    float g = ssq * sc1 * sc1;
    #pragma unroll
    for (int off = 1; off < 64; off <<= 1) g += __shfl_xor(g, off);
    if ((tid & 63) == 0) gw[tid >> 6] = g;
    __syncthreads();
    if (tid == 0) gss = 1.0f / fmaxf(sqrtf(gw[0] + gw[1] + gw[2] + gw[3]), 1e-12f);
    __syncthreads();
    const float gsc = gss;
    float* op = out + (size_t)n * (K_CL * D_CH) + k * D_CH + d0;
    #pragma unroll
    for (int c = 0; c < 4; ++c) {
        *(float4*)(op + (c << 2)) =
            make_float4(v[4*c+0]*gsc, v[4*c+1]*gsc, v[4*c+2]*gsc, v[4*c+3]*gsc);
    }
}

extern "C" void kernel_launch(void* const* d_in, const int* in_sizes, int n_in,
                              void* d_out, int out_size, void* d_ws, size_t ws_size,
                              hipStream_t stream)
{
    const float* x   = (const float*)d_in[0];
    const float* w   = (const float*)d_in[1];
    const float* cen = (const float*)d_in[2];
    float* out = (float*)d_out;

    float* aggp  = (float*)d_ws;                                    // [64][8][32][128] = 8 MB
    float* asump = aggp + (size_t)N_IMG * S_SPL * K_CL * D_CH;      // [64][8][32]

    netvlad_main<<<N_IMG * S_SPL, 256, 0, stream>>>(x, w, aggp, asump);
    netvlad_finish<<<N_IMG, 256, 0, stream>>>(aggp, asump, cen, out);
}